// Round 19
// baseline (406.500 us; speedup 1.0000x reference)
//
#include <hip/hip_runtime.h>
#include <hip/hip_bf16.h>
#include <math.h>

#define N_DIM 1024
#define L_SEQ 16384

typedef unsigned short ushort_t;
typedef __bf16 bf16x8 __attribute__((ext_vector_type(8)));
typedef float f32x4 __attribute__((ext_vector_type(4)));

#define FW_F32 1
#define FW_SPLIT 2
#define FW_TSPLIT 4
#define FW_ADDD 8
#define FW_MKAB 16
#define FW_TPRE 32

#define AS1 __attribute__((address_space(1)))
#define AS3 __attribute__((address_space(3)))

__device__ __forceinline__ void split2(float v, ushort_t& h, ushort_t& m) {
  union { __bf16 b; ushort_t u; } c;
  __bf16 bh = (__bf16)v;
  float fh = (float)bh;
  c.b = bh; h = c.u;
  c.b = (__bf16)(v - fh); m = c.u;
}

// ---------------- fused scale + 4-plane split: E = h*A -------------------
__global__ __launch_bounds__(256) void k_scalesplit(const float* __restrict__ A,
    const float* __restrict__ ls, float* __restrict__ E,
    ushort_t* __restrict__ set) {
  const size_t NN = (size_t)N_DIM * N_DIM;
  float hs = 0.5f * expf(ls[0]);
  int t = threadIdx.x;
  int r0 = blockIdx.x * 64 + ((t >> 4) << 2);
  int c0 = blockIdx.y * 64 + ((t & 15) << 2);
  float v[4][4];
#pragma unroll
  for (int i = 0; i < 4; ++i) {
    float4 f = *(const float4*)&A[(size_t)(r0 + i) * N_DIM + c0];
    v[i][0] = hs * f.x; v[i][1] = hs * f.y; v[i][2] = hs * f.z; v[i][3] = hs * f.w;
    *(float4*)&E[(size_t)(r0 + i) * N_DIM + c0] =
        make_float4(v[i][0], v[i][1], v[i][2], v[i][3]);
  }
  ushort_t h[4][4], m[4][4];
#pragma unroll
  for (int i = 0; i < 4; ++i)
#pragma unroll
    for (int j = 0; j < 4; ++j) split2(v[i][j], h[i][j], m[i][j]);
#pragma unroll
  for (int i = 0; i < 4; ++i) {
    size_t o = (size_t)(r0 + i) * N_DIM + c0;
    *(ushort4*)&set[o] = make_ushort4(h[i][0], h[i][1], h[i][2], h[i][3]);
    *(ushort4*)&set[NN + o] = make_ushort4(m[i][0], m[i][1], m[i][2], m[i][3]);
  }
#pragma unroll
  for (int j = 0; j < 4; ++j) {
    size_t o = (size_t)(c0 + j) * N_DIM + r0;
    *(ushort4*)&set[2 * NN + o] = make_ushort4(h[0][j], h[1][j], h[2][j], h[3][j]);
    *(ushort4*)&set[3 * NN + o] = make_ushort4(m[0][j], m[1][j], m[2][j], m[3][j]);
  }
}

// blocks 0..255: VT row0 = split(step*(B + S@B)); blocks 256..259: W row0 = split(C)
__global__ __launch_bounds__(256) void k_bbinit(ushort_t* __restrict__ VTset,
    ushort_t* __restrict__ Wset, const float* __restrict__ S,
    const float* __restrict__ B, const float* __restrict__ Cm,
    const float* __restrict__ ls) {
  const size_t KR = (size_t)128 * N_DIM;
  int bx = blockIdx.x;
  if (bx >= 256) {
    int i = (bx - 256) * 256 + threadIdx.x;
    ushort_t h, m; split2(Cm[i], h, m);
    Wset[i] = h; Wset[KR + i] = m;
    return;
  }
  int row = bx * 4 + (threadIdx.x >> 6);
  int lane = threadIdx.x & 63;
  const float* Sr = S + (size_t)row * N_DIM;
  float sum = 0.f;
  for (int k = lane; k < N_DIM; k += 64) sum += Sr[k] * B[k];
  for (int off = 32; off; off >>= 1) sum += __shfl_down(sum, off);
  if (lane == 0) {
    float step = expf(ls[0]);
    float bb = step * (B[row] + sum);
    ushort_t h, m; split2(bb, h, m);
    VTset[row] = h; VTset[KR + row] = m;
  }
}

// ---- combine tile: Kv[q*128+r] for q-tile rt (16 q's), r-tile ct (64 r's) -
__device__ __forceinline__ void combine_tile(
    ushort_t* lds, const ushort_t* __restrict__ Wset,
    const ushort_t* __restrict__ Vset, float* __restrict__ Kv,
    int rt, int ct, int t) {
  const size_t KR = (size_t)128 * N_DIM;
  const ushort_t* Ah = Wset;
  const ushort_t* Amm = Wset + KR;
  const ushort_t* Bh = Vset;
  const ushort_t* Bm = Vset + KR;
  const int lane = t & 63, w = t >> 6;
  const int lrow = lane & 15, kg = lane >> 4;

  auto stageS = [&](int buf, int k0) {
    ushort_t* base = lds + buf * 5120;
    if (t < 128) {
      int lvl = t >> 6, rem = t & 63, kcc = rem >> 4, i = rem & 15;
      const ushort_t* src =
          (lvl ? Amm : Ah) + (size_t)(rt * 16 + i) * N_DIM + k0 + kcc * 8;
      __builtin_amdgcn_global_load_lds((const AS1 void*)src,
                                       (AS3 void*)(base + t * 8), 16, 0, 0);
    }
#pragma unroll
    for (int it = 0; it < 2; ++it) {
      int t2 = t + it * 256;
      int lvl = t2 >> 8, rem = t2 & 255, kcc = rem >> 6, c = rem & 63;
      const ushort_t* src =
          (lvl ? Bm : Bh) + (size_t)(ct * 64 + c) * N_DIM + k0 + kcc * 8;
      __builtin_amdgcn_global_load_lds(
          (const AS1 void*)src, (AS3 void*)(base + 1024 + t2 * 8), 16, 0, 0);
    }
  };

  f32x4 acc = (f32x4){0.f, 0.f, 0.f, 0.f};
  const int aO = kg * 128 + lrow * 8;
  const int bO = 1024 + kg * 512 + (w * 16 + lrow) * 8;

  stageS(0, 0);
  stageS(1, 32);
  for (int ks = 0; ks < 32; ++ks) {
    int cur = ks % 3;
    if (ks < 30) {
      stageS((ks + 2) % 3, (ks + 2) * 32);
      if (w < 2) asm volatile("s_waitcnt vmcnt(6)" ::: "memory");
      else       asm volatile("s_waitcnt vmcnt(4)" ::: "memory");
    } else if (ks == 30) {
      if (w < 2) asm volatile("s_waitcnt vmcnt(3)" ::: "memory");
      else       asm volatile("s_waitcnt vmcnt(2)" ::: "memory");
    } else {
      asm volatile("s_waitcnt vmcnt(0)" ::: "memory");
    }
    __builtin_amdgcn_s_barrier();
    __builtin_amdgcn_sched_barrier(0);
    const ushort_t* b = lds + cur * 5120;
    bf16x8 a0 = *(const bf16x8*)&b[aO];
    bf16x8 a1 = *(const bf16x8*)&b[aO + 512];
    bf16x8 b0v = *(const bf16x8*)&b[bO];
    bf16x8 b1v = *(const bf16x8*)&b[bO + 2048];
    acc = __builtin_amdgcn_mfma_f32_16x16x32_bf16(a0, b0v, acc, 0, 0, 0);
    acc = __builtin_amdgcn_mfma_f32_16x16x32_bf16(a0, b1v, acc, 0, 0, 0);
    acc = __builtin_amdgcn_mfma_f32_16x16x32_bf16(a1, b0v, acc, 0, 0, 0);
    acc = __builtin_amdgcn_mfma_f32_16x16x32_bf16(a1, b1v, acc, 0, 0, 0);
    if (ks < 31) __builtin_amdgcn_s_barrier();
  }

  int rcol = ct * 64 + w * 16 + lrow;
#pragma unroll
  for (int j = 0; j < 4; ++j) {
    int q = rt * 16 + kg * 4 + j;
    Kv[q * 128 + rcol] = acc[j];
  }
}

// ---- standalone skinny quarter-tile (mode 2 chains); uses lds[0..6144) ----
__device__ __forceinline__ void skinny_q(
    ushort_t* lds, const ushort_t* __restrict__ SkB, ushort_t* __restrict__ Ka,
    int srcOff, int dstOff, int cnt, int id, int t) {
  const size_t NN = (size_t)N_DIM * N_DIM;
  const size_t KR = (size_t)128 * N_DIM;
  int rt = id >> 6, c16 = id & 63;
  if (rt * 16 >= cnt) return;
  const int lane = t & 63, w = t >> 6;
  const ushort_t* Ah = Ka;
  const ushort_t* Amm = Ka + KR;
  const ushort_t* Bh = SkB;
  const ushort_t* Bm = SkB + NN;

  auto stq = [&](int buf, int k0) {  // 1 load per thread
    ushort_t* base = lds + buf * 2048;
    if (t < 128) {
      int pl = t >> 6, rem = t & 63, kc = rem >> 4, row = rem & 15;
      const ushort_t* src = (pl ? Amm : Ah) +
          (size_t)(srcOff + rt * 16 + row) * N_DIM + k0 + kc * 8;
      __builtin_amdgcn_global_load_lds((const AS1 void*)src,
                                       (AS3 void*)(base + t * 8), 16, 0, 0);
    } else {
      int t2 = t - 128;
      int pl = t2 >> 6, rem = t2 & 63, kc = rem >> 4, row = rem & 15;
      const ushort_t* src = (pl ? Bm : Bh) +
          (size_t)(c16 * 16 + row) * N_DIM + k0 + kc * 8;
      __builtin_amdgcn_global_load_lds((const AS1 void*)src,
                                       (AS3 void*)(base + 1024 + t2 * 8), 16, 0, 0);
    }
  };

  f32x4 acc = (f32x4){0.f, 0.f, 0.f, 0.f};
  const int lrow = lane & 15, kg = lane >> 4;

  stq(0, 0);
  stq(1, 32);
  for (int ks = 0; ks < 32; ++ks) {
    int cur = ks % 3;
    if (ks < 30) {
      stq((ks + 2) % 3, (ks + 2) * 32);
      asm volatile("s_waitcnt vmcnt(2)" ::: "memory");
    } else if (ks == 30) {
      asm volatile("s_waitcnt vmcnt(1)" ::: "memory");
    } else {
      asm volatile("s_waitcnt vmcnt(0)" ::: "memory");
    }
    __builtin_amdgcn_s_barrier();
    __builtin_amdgcn_sched_barrier(0);
    if (w == 0) {
      const ushort_t* b = lds + cur * 2048;
      bf16x8 a0 = *(const bf16x8*)&b[kg * 128 + lrow * 8];
      bf16x8 a1 = *(const bf16x8*)&b[512 + kg * 128 + lrow * 8];
      bf16x8 b0 = *(const bf16x8*)&b[1024 + kg * 128 + lrow * 8];
      bf16x8 b1 = *(const bf16x8*)&b[1536 + kg * 128 + lrow * 8];
      acc = __builtin_amdgcn_mfma_f32_16x16x32_bf16(a0, b0, acc, 0, 0, 0);
      acc = __builtin_amdgcn_mfma_f32_16x16x32_bf16(a0, b1, acc, 0, 0, 0);
      acc = __builtin_amdgcn_mfma_f32_16x16x32_bf16(a1, b0, acc, 0, 0, 0);
      acc = __builtin_amdgcn_mfma_f32_16x16x32_bf16(a1, b1, acc, 0, 0, 0);
    }
    if (ks < 31) __builtin_amdgcn_s_barrier();
  }

  if (w == 0) {
    int col = c16 * 16 + lrow;
#pragma unroll
    for (int j = 0; j < 4; ++j) {
      int irl = kg * 4 + j;
      if (rt * 16 + irl < cnt) {
        ushort_t h, m; split2(acc[j], h, m);
        Ka[(size_t)(dstOff + rt * 16 + irl) * N_DIM + col] = h;
        Ka[KR + (size_t)(dstOff + rt * 16 + irl) * N_DIM + col] = m;
      }
    }
  }
}

// ---------------- fused full-K GEMM: squaring 64x64 depth-2 + INTERLEAVED --
// skinny quarter-tile. mode 0: squaring only (16x16). mode 1: squaring +
// interleaved skinny (16x16 uniform). mode 2: skinny quarters + combine ride
// (16x9: y<8 skinny, y==8 x<4 combine chunk). mode 3: combine chunk only (4,1).
// LDS 60 KB: squaring 3 bufs x 16 KB @0; skinny 3 bufs x 4 KB @24576 ushorts.
__global__ __launch_bounds__(256) void gemm4f(
    const ushort_t* __restrict__ Qa, const ushort_t* __restrict__ Qbt,
    const float* __restrict__ D, float* __restrict__ Cf,
    ushort_t* __restrict__ Oset, ushort_t* __restrict__ Oset2, int flags,
    const ushort_t* __restrict__ SkB, ushort_t* __restrict__ Ka,
    int srcOff, int dstOff, int cnt, int mode,
    const ushort_t* __restrict__ Vt, float* __restrict__ Kv, int chunk) {
  const size_t NN = (size_t)N_DIM * N_DIM;
  const size_t KR = (size_t)128 * N_DIM;
  __shared__ __align__(16) ushort_t lds[30720];  // 60 KB
  int t = threadIdx.x;
  const int lane = t & 63, w = t >> 6;
  int id = (int)blockIdx.y * 16 + (int)blockIdx.x;

  if (mode == 3) {
    combine_tile(lds, Ka, Vt, Kv, 2 * chunk + ((int)blockIdx.x >> 1),
                 (int)blockIdx.x & 1, t);
    return;
  }
  if (mode == 2) {
    if ((int)blockIdx.y == 8) {
      if ((int)blockIdx.x < 4 && chunk >= 0)
        combine_tile(lds, Ka, Vt, Kv, 2 * chunk + ((int)blockIdx.x >> 1),
                     (int)blockIdx.x & 1, t);
      return;
    }
    skinny_q(lds, SkB, Ka, srcOff, dstOff, cnt, id, t);
    return;
  }

  int m0 = blockIdx.x * 64, n0 = blockIdx.y * 64;
  int r = t & 63, kc = t >> 6;
  const ushort_t* gA[2] = {Qa, Qa + NN};
  const ushort_t* gB[2] = {Qbt, Qbt + NN};
  size_t aoff = (size_t)(m0 + r) * N_DIM + kc * 8;
  size_t boff = (size_t)(n0 + r) * N_DIM + kc * 8;

  // skinny identity
  int rt = id >> 6, c16 = id & 63;
  bool hasSk = (mode == 1) && (rt * 16 < cnt);
  const ushort_t* skAh = Ka;
  const ushort_t* skAm = Ka + KR;
  const ushort_t* skBh = SkB;
  const ushort_t* skBm = SkB ? SkB + NN : SkB;

  auto stage = [&](int buf, int k0) {  // 4 loads per thread
    ushort_t* dst = lds + buf * 8192;
#pragma unroll
    for (int L = 0; L < 2; ++L) {
      __builtin_amdgcn_global_load_lds(
          (const AS1 void*)(gA[L] + aoff + k0),
          (AS3 void*)(dst + L * 2048 + t * 8), 16, 0, 0);
      __builtin_amdgcn_global_load_lds(
          (const AS1 void*)(gB[L] + boff + k0),
          (AS3 void*)(dst + 4096 + L * 2048 + t * 8), 16, 0, 0);
    }
  };
  auto stq = [&](int buf, int k0) {  // 1 load per thread (skinny)
    ushort_t* base = lds + 24576 + buf * 2048;
    if (t < 128) {
      int pl = t >> 6, rem = t & 63, skc = rem >> 4, row = rem & 15;
      const ushort_t* src = (pl ? skAm : skAh) +
          (size_t)(srcOff + rt * 16 + row) * N_DIM + k0 + skc * 8;
      __builtin_amdgcn_global_load_lds((const AS1 void*)src,
                                       (AS3 void*)(base + t * 8), 16, 0, 0);
    } else {
      int t2 = t - 128;
      int pl = t2 >> 6, rem = t2 & 63, skc = rem >> 4, row = rem & 15;
      const ushort_t* src = (pl ? skBm : skBh) +
          (size_t)(c16 * 16 + row) * N_DIM + k0 + skc * 8;
      __builtin_amdgcn_global_load_lds((const AS1 void*)src,
                                       (AS3 void*)(base + 1024 + t2 * 8), 16, 0, 0);
    }
  };

  f32x4 acc[2][2];
#pragma unroll
  for (int i = 0; i < 2; ++i)
#pragma unroll
    for (int j = 0; j < 2; ++j) acc[i][j] = (f32x4){0.f, 0.f, 0.f, 0.f};
  f32x4 skacc = (f32x4){0.f, 0.f, 0.f, 0.f};

  const int wm = (w >> 1) * 32, wn = (w & 1) * 32;
  const int lrow = lane & 15, kg = lane >> 4;
  const int aIdx0 = kg * 512 + (wm + lrow) * 8;
  const int bIdx0 = 4096 + kg * 512 + (wn + lrow) * 8;

#pragma unroll
  for (int p = 0; p < 2; ++p) {
    stage(p, p * 32);
    if (hasSk) stq(p, p * 32);
  }
  for (int ks = 0; ks < 32; ++ks) {
    int cur = ks % 3;
    if (ks < 30) {
      stage((ks + 2) % 3, (ks + 2) * 32);
      if (hasSk) {
        stq((ks + 2) % 3, (ks + 2) * 32);
        asm volatile("s_waitcnt vmcnt(10)" ::: "memory");
      } else {
        asm volatile("s_waitcnt vmcnt(8)" ::: "memory");
      }
    } else if (ks == 30) {
      if (hasSk) asm volatile("s_waitcnt vmcnt(5)" ::: "memory");
      else       asm volatile("s_waitcnt vmcnt(4)" ::: "memory");
    } else {
      asm volatile("s_waitcnt vmcnt(0)" ::: "memory");
    }
    __builtin_amdgcn_s_barrier();
    __builtin_amdgcn_sched_barrier(0);
    const ushort_t* buf = lds + cur * 8192;
    bf16x8 a[2][2], b[2][2];
#pragma unroll
    for (int L = 0; L < 2; ++L) {
#pragma unroll
      for (int mi = 0; mi < 2; ++mi)
        a[L][mi] = *(const bf16x8*)&buf[L * 2048 + aIdx0 + mi * 128];
#pragma unroll
      for (int ni = 0; ni < 2; ++ni)
        b[L][ni] = *(const bf16x8*)&buf[bIdx0 + L * 2048 + ni * 128];
    }
#pragma unroll
    for (int mi = 0; mi < 2; ++mi)
#pragma unroll
      for (int ni = 0; ni < 2; ++ni) {
        f32x4 c = acc[mi][ni];
        c = __builtin_amdgcn_mfma_f32_16x16x32_bf16(a[0][mi], b[0][ni], c, 0, 0, 0);
        c = __builtin_amdgcn_mfma_f32_16x16x32_bf16(a[0][mi], b[1][ni], c, 0, 0, 0);
        c = __builtin_amdgcn_mfma_f32_16x16x32_bf16(a[1][mi], b[0][ni], c, 0, 0, 0);
        c = __builtin_amdgcn_mfma_f32_16x16x32_bf16(a[1][mi], b[1][ni], c, 0, 0, 0);
        acc[mi][ni] = c;
      }
    if (hasSk && w == 0) {
      const ushort_t* sb = lds + 24576 + cur * 2048;
      bf16x8 sa0 = *(const bf16x8*)&sb[kg * 128 + lrow * 8];
      bf16x8 sa1 = *(const bf16x8*)&sb[512 + kg * 128 + lrow * 8];
      bf16x8 sb0 = *(const bf16x8*)&sb[1024 + kg * 128 + lrow * 8];
      bf16x8 sb1 = *(const bf16x8*)&sb[1536 + kg * 128 + lrow * 8];
      skacc = __builtin_amdgcn_mfma_f32_16x16x32_bf16(sa0, sb0, skacc, 0, 0, 0);
      skacc = __builtin_amdgcn_mfma_f32_16x16x32_bf16(sa0, sb1, skacc, 0, 0, 0);
      skacc = __builtin_amdgcn_mfma_f32_16x16x32_bf16(sa1, sb0, skacc, 0, 0, 0);
      skacc = __builtin_amdgcn_mfma_f32_16x16x32_bf16(sa1, sb1, skacc, 0, 0, 0);
    }
    if (ks < 31) __builtin_amdgcn_s_barrier();
  }

  // ---- squaring epilogue ----
#pragma unroll
  for (int mi = 0; mi < 2; ++mi)
#pragma unroll
    for (int ni = 0; ni < 2; ++ni) {
      int rowb = m0 + wm + mi * 16 + kg * 4;
      int col = n0 + wn + ni * 16 + lrow;
      float vv[4];
#pragma unroll
      for (int j = 0; j < 4; ++j) vv[j] = acc[mi][ni][j];
      if (flags & FW_TPRE) {
        ushort_t h[4], m[4];
#pragma unroll
        for (int j = 0; j < 4; ++j) split2(vv[j], h[j], m[j]);
        size_t o = (size_t)col * N_DIM + rowb;
        *(ushort4*)&Oset2[2 * NN + o] = make_ushort4(h[0], h[1], h[2], h[3]);
        *(ushort4*)&Oset2[3 * NN + o] = make_ushort4(m[0], m[1], m[2], m[3]);
      }
      if (flags & FW_ADDD) {
#pragma unroll
        for (int j = 0; j < 4; ++j) vv[j] += D[(size_t)(rowb + j) * N_DIM + col];
      }
      if (flags & FW_F32) {
#pragma unroll
        for (int j = 0; j < 4; ++j) Cf[(size_t)(rowb + j) * N_DIM + col] = vv[j];
      }
      if (flags & FW_MKAB) {
#pragma unroll
        for (int j = 0; j < 4; ++j)
          vv[j] = 2.0f * vv[j] + ((rowb + j) == col ? 1.0f : 0.0f);
      }
      if (flags & (FW_SPLIT | FW_TSPLIT)) {
        ushort_t h[4], m[4];
#pragma unroll
        for (int j = 0; j < 4; ++j) split2(vv[j], h[j], m[j]);
        if (flags & FW_SPLIT) {
#pragma unroll
          for (int j = 0; j < 4; ++j) {
            size_t o = (size_t)(rowb + j) * N_DIM + col;
            Oset[o] = h[j]; Oset[NN + o] = m[j];
          }
        }
        if (flags & FW_TSPLIT) {
          size_t o = (size_t)col * N_DIM + rowb;
          *(ushort4*)&Oset[2 * NN + o] = make_ushort4(h[0], h[1], h[2], h[3]);
          *(ushort4*)&Oset[3 * NN + o] = make_ushort4(m[0], m[1], m[2], m[3]);
        }
      }
    }

  // ---- skinny epilogue ----
  if (hasSk && w == 0) {
    int col = c16 * 16 + lrow;
#pragma unroll
    for (int j = 0; j < 4; ++j) {
      int irl = kg * 4 + j;
      if (rt * 16 + irl < cnt) {
        ushort_t h, m; split2(skacc[j], h, m);
        Ka[(size_t)(dstOff + rt * 16 + irl) * N_DIM + col] = h;
        Ka[KR + (size_t)(dstOff + rt * 16 + irl) * N_DIM + col] = m;
      }
    }
  }
}

// ---------------- causal convolution --------------------------------------
__global__ __launch_bounds__(256) void conv_k(const float* __restrict__ Kv,
    const float* __restrict__ u, float* __restrict__ y) {
  const int CT = 1024, CJ = 256, LCH = 1024;
  int t0 = blockIdx.x * CT;
  int l0 = blockIdx.y * LCH;
  if (l0 > t0 + CT - 1) return;
  __shared__ __align__(16) float Ks[CJ];
  __shared__ __align__(16) float us[CT + CJ + 8];
  int tid = threadIdx.x;
  float acc0 = 0.f, acc1 = 0.f, acc2 = 0.f, acc3 = 0.f;
  int ltEnd = l0 + LCH; if (ltEnd > t0 + CT) ltEnd = t0 + CT;
  for (int lt = l0; lt < ltEnd; lt += CJ) {
    __syncthreads();
    Ks[tid] = Kv[lt + tid];
    int ub = t0 - lt - (CJ - 1);
    for (int s = tid; s < CT + CJ + 4; s += 256) {
      int g = ub + s;
      us[s] = (g >= 0 && g < L_SEQ) ? u[g] : 0.f;
    }
    __syncthreads();
    const float4* u4 = (const float4*)us;
    float4 wa = u4[tid];
#pragma unroll 4
    for (int jb = 0; jb < CJ / 4; ++jb) {
      float4 wb = u4[tid + jb + 1];
      float4 k4 = *(const float4*)&Ks[CJ - 4 - (jb << 2)];
      acc0 += k4.w * wa.x + k4.z * wa.y + k4.y * wa.z + k4.x * wa.w;
      acc1 += k4.w * wa.y + k4.z * wa.z + k4.y * wa.w + k4.x * wb.x;
      acc2 += k4.w * wa.z + k4.z * wa.w + k4.y * wb.x + k4.x * wb.y;
      acc3 += k4.w * wa.w + k4.z * wb.x + k4.y * wb.y + k4.x * wb.z;
      wa = wb;
    }
  }
  int t = t0 + (tid << 2);
  atomicAdd(&y[t + 0], acc0);
  atomicAdd(&y[t + 1], acc1);
  atomicAdd(&y[t + 2], acc2);
  atomicAdd(&y[t + 3], acc3);
}

// ---------------- host ----------------

extern "C" void kernel_launch(void* const* d_in, const int* in_sizes, int n_in,
                              void* d_out, int out_size, void* d_ws, size_t ws_size,
                              hipStream_t stream) {
  const float* u  = (const float*)d_in[0];
  const float* A  = (const float*)d_in[1];
  const float* B  = (const float*)d_in[2];
  const float* Cm = (const float*)d_in[3];
  const float* ls = (const float*)d_in[4];
  float* y  = (float*)d_out;
  float* ws = (float*)d_ws;

  const int N = N_DIM;
  const size_t NN = (size_t)N * N;
  const size_t KR = (size_t)128 * N;
  float* b0 = ws;                     // E -> S
  float* b2 = b0 + NN;                // S1
  float* Kv = b2 + NN;                // L (=128*128)
  ushort_t* setA = (ushort_t*)(Kv + L_SEQ);
  ushort_t* setB = setA + 4 * NN;
  ushort_t* setC = setB + 4 * NN;
  ushort_t* VTset = setC + 4 * NN;    // {H,M} each 128xN
  ushort_t* Wset = VTset + 2 * KR;

  hipMemsetAsync(y, 0, (size_t)L_SEQ * sizeof(float), stream);

  dim3 g16(16, 16);
  dim3 gQC(16, 9);      // 128 quarter-tiles + combine-chunk ride
  dim3 gC4(4, 1);       // final combine chunk

  // E = (step/2)*A ; 4-plane splits -> setA
  k_scalesplit<<<g16, 256, 0, stream>>>(A, ls, b0, setA);
  // E2 = E*E; epilogue: T-splits(E2)->setB, S1=E2+E f32->b2, row-splits(S1)->setC
  gemm4f<<<g16, 256, 0, stream>>>(setA, setA + 2 * NN, b0, b2, setC, setB,
                                  FW_TPRE | FW_ADDD | FW_F32 | FW_SPLIT,
                                  nullptr, nullptr, 0, 0, 0, 0,
                                  nullptr, nullptr, -1);
  // S = S1*E2 + S1; epilogue: f32 S->b0, Ab=2S+I 4 planes -> setA
  gemm4f<<<g16, 256, 0, stream>>>(setC, setB + 2 * NN, b2, b0, setA, nullptr,
                                  FW_ADDD | FW_F32 | FW_MKAB | FW_SPLIT | FW_TSPLIT,
                                  nullptr, nullptr, 0, 0, 0, 0,
                                  nullptr, nullptr, -1);
  // VT row0 = split(Bb); W row0 = split(C)
  k_bbinit<<<260, 256, 0, stream>>>(VTset, Wset, b0, B, Cm, ls);

  // 12 fused steps (e=0..11): squaring with INTERLEAVED skinny quarters.
  ushort_t* cur = setA;
  ushort_t* oth = setB;
  for (int e = 0; e < 12; ++e) {
    int right = (e < 7);
    int s = 1 << (right ? e : (e - 7));
    ushort_t* Ka = right ? VTset : Wset;
    const ushort_t* SkB = right ? cur : cur + 2 * NN;
    int fl = (e == 11) ? FW_TSPLIT : (FW_SPLIT | FW_TSPLIT);
    gemm4f<<<g16, 256, 0, stream>>>(cur, cur + 2 * NN, nullptr, nullptr,
                                    oth, nullptr, fl, SkB, Ka, 0, s, s, 1,
                                    nullptr, nullptr, -1);
    ushort_t* tmp = cur; cur = oth; oth = tmp;
  }
  // cur = Ab^4096. Build W rows [32,128) via 3 chained 32-row quarter passes,
  // each carrying the combine chunk for the previously-finalized 32 q-rows.
  const ushort_t* Q12T = cur + 2 * NN;
  for (int p = 0; p < 3; ++p)
    gemm4f<<<gQC, 256, 0, stream>>>(cur, cur, nullptr, nullptr,
                                    nullptr, nullptr, 0, Q12T, Wset,
                                    32 * p, 32 + 32 * p, 32, 2,
                                    VTset, Kv, p);
  // final combine chunk: q in [96,128)
  gemm4f<<<gC4, 256, 0, stream>>>(nullptr, nullptr, nullptr, nullptr,
                                  nullptr, nullptr, 0, nullptr, Wset,
                                  0, 0, 0, 3, VTset, Kv, 3);
  // y = causal conv(K, u)
  conv_k<<<g16, 256, 0, stream>>>(Kv, u, y);
}

// Round 20
// 393.550 us; speedup vs baseline: 1.0329x; 1.0329x over previous
//
#include <hip/hip_runtime.h>
#include <hip/hip_bf16.h>
#include <math.h>

#define N_DIM 1024
#define L_SEQ 16384

typedef unsigned short ushort_t;
typedef __bf16 bf16x8 __attribute__((ext_vector_type(8)));
typedef float f32x4 __attribute__((ext_vector_type(4)));

#define FW_F32 1
#define FW_SPLIT 2
#define FW_TSPLIT 4
#define FW_ADDD 8
#define FW_MKAB 16
#define FW_TPRE 32

#define AS1 __attribute__((address_space(1)))
#define AS3 __attribute__((address_space(3)))

__device__ __forceinline__ void split2(float v, ushort_t& h, ushort_t& m) {
  union { __bf16 b; ushort_t u; } c;
  __bf16 bh = (__bf16)v;
  float fh = (float)bh;
  c.b = bh; h = c.u;
  c.b = (__bf16)(v - fh); m = c.u;
}

// ---------------- fused scale + 4-plane split: E = h*A -------------------
__global__ __launch_bounds__(256) void k_scalesplit(const float* __restrict__ A,
    const float* __restrict__ ls, float* __restrict__ E,
    ushort_t* __restrict__ set) {
  const size_t NN = (size_t)N_DIM * N_DIM;
  float hs = 0.5f * expf(ls[0]);
  int t = threadIdx.x;
  int r0 = blockIdx.x * 64 + ((t >> 4) << 2);
  int c0 = blockIdx.y * 64 + ((t & 15) << 2);
  float v[4][4];
#pragma unroll
  for (int i = 0; i < 4; ++i) {
    float4 f = *(const float4*)&A[(size_t)(r0 + i) * N_DIM + c0];
    v[i][0] = hs * f.x; v[i][1] = hs * f.y; v[i][2] = hs * f.z; v[i][3] = hs * f.w;
    *(float4*)&E[(size_t)(r0 + i) * N_DIM + c0] =
        make_float4(v[i][0], v[i][1], v[i][2], v[i][3]);
  }
  ushort_t h[4][4], m[4][4];
#pragma unroll
  for (int i = 0; i < 4; ++i)
#pragma unroll
    for (int j = 0; j < 4; ++j) split2(v[i][j], h[i][j], m[i][j]);
#pragma unroll
  for (int i = 0; i < 4; ++i) {
    size_t o = (size_t)(r0 + i) * N_DIM + c0;
    *(ushort4*)&set[o] = make_ushort4(h[i][0], h[i][1], h[i][2], h[i][3]);
    *(ushort4*)&set[NN + o] = make_ushort4(m[i][0], m[i][1], m[i][2], m[i][3]);
  }
#pragma unroll
  for (int j = 0; j < 4; ++j) {
    size_t o = (size_t)(c0 + j) * N_DIM + r0;
    *(ushort4*)&set[2 * NN + o] = make_ushort4(h[0][j], h[1][j], h[2][j], h[3][j]);
    *(ushort4*)&set[3 * NN + o] = make_ushort4(m[0][j], m[1][j], m[2][j], m[3][j]);
  }
}

// blocks 0..255: VT row0 = split(step*(B + S@B)); blocks 256..259: W row0 = split(C)
__global__ __launch_bounds__(256) void k_bbinit(ushort_t* __restrict__ VTset,
    ushort_t* __restrict__ Wset, const float* __restrict__ S,
    const float* __restrict__ B, const float* __restrict__ Cm,
    const float* __restrict__ ls) {
  const size_t KR = (size_t)128 * N_DIM;
  int bx = blockIdx.x;
  if (bx >= 256) {
    int i = (bx - 256) * 256 + threadIdx.x;
    ushort_t h, m; split2(Cm[i], h, m);
    Wset[i] = h; Wset[KR + i] = m;
    return;
  }
  int row = bx * 4 + (threadIdx.x >> 6);
  int lane = threadIdx.x & 63;
  const float* Sr = S + (size_t)row * N_DIM;
  float sum = 0.f;
  for (int k = lane; k < N_DIM; k += 64) sum += Sr[k] * B[k];
  for (int off = 32; off; off >>= 1) sum += __shfl_down(sum, off);
  if (lane == 0) {
    float step = expf(ls[0]);
    float bb = step * (B[row] + sum);
    ushort_t h, m; split2(bb, h, m);
    VTset[row] = h; VTset[KR + row] = m;
  }
}

// ---- standalone skinny quarter-tile (mode 2 chains); uses lds[0..6144) ----
__device__ __forceinline__ void skinny_q(
    ushort_t* lds, const ushort_t* __restrict__ SkB, ushort_t* __restrict__ Ka,
    int srcOff, int dstOff, int cnt, int id, int t) {
  const size_t NN = (size_t)N_DIM * N_DIM;
  const size_t KR = (size_t)128 * N_DIM;
  int rt = id >> 6, c16 = id & 63;
  if (rt * 16 >= cnt) return;
  const int lane = t & 63, w = t >> 6;
  const ushort_t* Ah = Ka;
  const ushort_t* Amm = Ka + KR;
  const ushort_t* Bh = SkB;
  const ushort_t* Bm = SkB + NN;

  auto stq = [&](int buf, int k0) {  // 1 load per thread
    ushort_t* base = lds + buf * 2048;
    if (t < 128) {
      int pl = t >> 6, rem = t & 63, kc = rem >> 4, row = rem & 15;
      const ushort_t* src = (pl ? Amm : Ah) +
          (size_t)(srcOff + rt * 16 + row) * N_DIM + k0 + kc * 8;
      __builtin_amdgcn_global_load_lds((const AS1 void*)src,
                                       (AS3 void*)(base + t * 8), 16, 0, 0);
    } else {
      int t2 = t - 128;
      int pl = t2 >> 6, rem = t2 & 63, kc = rem >> 4, row = rem & 15;
      const ushort_t* src = (pl ? Bm : Bh) +
          (size_t)(c16 * 16 + row) * N_DIM + k0 + kc * 8;
      __builtin_amdgcn_global_load_lds((const AS1 void*)src,
                                       (AS3 void*)(base + 1024 + t2 * 8), 16, 0, 0);
    }
  };

  f32x4 acc = (f32x4){0.f, 0.f, 0.f, 0.f};
  const int lrow = lane & 15, kg = lane >> 4;

  stq(0, 0);
  stq(1, 32);
  for (int ks = 0; ks < 32; ++ks) {
    int cur = ks % 3;
    if (ks < 30) {
      stq((ks + 2) % 3, (ks + 2) * 32);
      asm volatile("s_waitcnt vmcnt(2)" ::: "memory");
    } else if (ks == 30) {
      asm volatile("s_waitcnt vmcnt(1)" ::: "memory");
    } else {
      asm volatile("s_waitcnt vmcnt(0)" ::: "memory");
    }
    __builtin_amdgcn_s_barrier();
    __builtin_amdgcn_sched_barrier(0);
    if (w == 0) {
      const ushort_t* b = lds + cur * 2048;
      bf16x8 a0 = *(const bf16x8*)&b[kg * 128 + lrow * 8];
      bf16x8 a1 = *(const bf16x8*)&b[512 + kg * 128 + lrow * 8];
      bf16x8 b0 = *(const bf16x8*)&b[1024 + kg * 128 + lrow * 8];
      bf16x8 b1 = *(const bf16x8*)&b[1536 + kg * 128 + lrow * 8];
      acc = __builtin_amdgcn_mfma_f32_16x16x32_bf16(a0, b0, acc, 0, 0, 0);
      acc = __builtin_amdgcn_mfma_f32_16x16x32_bf16(a0, b1, acc, 0, 0, 0);
      acc = __builtin_amdgcn_mfma_f32_16x16x32_bf16(a1, b0, acc, 0, 0, 0);
      acc = __builtin_amdgcn_mfma_f32_16x16x32_bf16(a1, b1, acc, 0, 0, 0);
    }
    if (ks < 31) __builtin_amdgcn_s_barrier();
  }

  if (w == 0) {
    int col = c16 * 16 + lrow;
#pragma unroll
    for (int j = 0; j < 4; ++j) {
      int irl = kg * 4 + j;
      if (rt * 16 + irl < cnt) {
        ushort_t h, m; split2(acc[j], h, m);
        Ka[(size_t)(dstOff + rt * 16 + irl) * N_DIM + col] = h;
        Ka[KR + (size_t)(dstOff + rt * 16 + irl) * N_DIM + col] = m;
      }
    }
  }
}

// ---------------- fused full-K GEMM: squaring 64x64 depth-2 + INTERLEAVED --
// skinny quarter-tile. mode 0: squaring only. mode 1: squaring + interleaved
// skinny (grid 16x16 uniform). mode 2: skinny quarters only.
// LDS 60 KB: squaring 3 bufs x 16 KB @0; skinny 3 bufs x 4 KB @24576 ushorts.
// -> 2 blocks/CU.
__global__ __launch_bounds__(256) void gemm4f(
    const ushort_t* __restrict__ Qa, const ushort_t* __restrict__ Qbt,
    const float* __restrict__ D, float* __restrict__ Cf,
    ushort_t* __restrict__ Oset, ushort_t* __restrict__ Oset2, int flags,
    const ushort_t* __restrict__ SkB, ushort_t* __restrict__ Ka,
    int srcOff, int dstOff, int cnt, int mode) {
  const size_t NN = (size_t)N_DIM * N_DIM;
  const size_t KR = (size_t)128 * N_DIM;
  __shared__ __align__(16) ushort_t lds[30720];  // 60 KB
  int t = threadIdx.x;
  const int lane = t & 63, w = t >> 6;
  int id = (int)blockIdx.y * 16 + (int)blockIdx.x;

  if (mode == 2) {
    skinny_q(lds, SkB, Ka, srcOff, dstOff, cnt, id, t);
    return;
  }

  int m0 = blockIdx.x * 64, n0 = blockIdx.y * 64;
  int r = t & 63, kc = t >> 6;
  const ushort_t* gA[2] = {Qa, Qa + NN};
  const ushort_t* gB[2] = {Qbt, Qbt + NN};
  size_t aoff = (size_t)(m0 + r) * N_DIM + kc * 8;
  size_t boff = (size_t)(n0 + r) * N_DIM + kc * 8;

  // skinny identity
  int rt = id >> 6, c16 = id & 63;
  bool hasSk = (mode == 1) && (rt * 16 < cnt);
  const ushort_t* skAh = Ka;
  const ushort_t* skAm = Ka + KR;
  const ushort_t* skBh = SkB;
  const ushort_t* skBm = SkB ? SkB + NN : SkB;

  auto stage = [&](int buf, int k0) {  // 4 loads per thread
    ushort_t* dst = lds + buf * 8192;
#pragma unroll
    for (int L = 0; L < 2; ++L) {
      __builtin_amdgcn_global_load_lds(
          (const AS1 void*)(gA[L] + aoff + k0),
          (AS3 void*)(dst + L * 2048 + t * 8), 16, 0, 0);
      __builtin_amdgcn_global_load_lds(
          (const AS1 void*)(gB[L] + boff + k0),
          (AS3 void*)(dst + 4096 + L * 2048 + t * 8), 16, 0, 0);
    }
  };
  auto stq = [&](int buf, int k0) {  // 1 load per thread (skinny)
    ushort_t* base = lds + 24576 + buf * 2048;
    if (t < 128) {
      int pl = t >> 6, rem = t & 63, skc = rem >> 4, row = rem & 15;
      const ushort_t* src = (pl ? skAm : skAh) +
          (size_t)(srcOff + rt * 16 + row) * N_DIM + k0 + skc * 8;
      __builtin_amdgcn_global_load_lds((const AS1 void*)src,
                                       (AS3 void*)(base + t * 8), 16, 0, 0);
    } else {
      int t2 = t - 128;
      int pl = t2 >> 6, rem = t2 & 63, skc = rem >> 4, row = rem & 15;
      const ushort_t* src = (pl ? skBm : skBh) +
          (size_t)(c16 * 16 + row) * N_DIM + k0 + skc * 8;
      __builtin_amdgcn_global_load_lds((const AS1 void*)src,
                                       (AS3 void*)(base + 1024 + t2 * 8), 16, 0, 0);
    }
  };

  f32x4 acc[2][2];
#pragma unroll
  for (int i = 0; i < 2; ++i)
#pragma unroll
    for (int j = 0; j < 2; ++j) acc[i][j] = (f32x4){0.f, 0.f, 0.f, 0.f};
  f32x4 skacc = (f32x4){0.f, 0.f, 0.f, 0.f};

  const int wm = (w >> 1) * 32, wn = (w & 1) * 32;
  const int lrow = lane & 15, kg = lane >> 4;
  const int aIdx0 = kg * 512 + (wm + lrow) * 8;
  const int bIdx0 = 4096 + kg * 512 + (wn + lrow) * 8;

#pragma unroll
  for (int p = 0; p < 2; ++p) {
    stage(p, p * 32);
    if (hasSk) stq(p, p * 32);
  }
  for (int ks = 0; ks < 32; ++ks) {
    int cur = ks % 3;
    if (ks < 30) {
      stage((ks + 2) % 3, (ks + 2) * 32);
      if (hasSk) {
        stq((ks + 2) % 3, (ks + 2) * 32);
        asm volatile("s_waitcnt vmcnt(10)" ::: "memory");
      } else {
        asm volatile("s_waitcnt vmcnt(8)" ::: "memory");
      }
    } else if (ks == 30) {
      if (hasSk) asm volatile("s_waitcnt vmcnt(5)" ::: "memory");
      else       asm volatile("s_waitcnt vmcnt(4)" ::: "memory");
    } else {
      asm volatile("s_waitcnt vmcnt(0)" ::: "memory");
    }
    __builtin_amdgcn_s_barrier();
    __builtin_amdgcn_sched_barrier(0);
    const ushort_t* buf = lds + cur * 8192;
    bf16x8 a[2][2], b[2][2];
#pragma unroll
    for (int L = 0; L < 2; ++L) {
#pragma unroll
      for (int mi = 0; mi < 2; ++mi)
        a[L][mi] = *(const bf16x8*)&buf[L * 2048 + aIdx0 + mi * 128];
#pragma unroll
      for (int ni = 0; ni < 2; ++ni)
        b[L][ni] = *(const bf16x8*)&buf[bIdx0 + L * 2048 + ni * 128];
    }
#pragma unroll
    for (int mi = 0; mi < 2; ++mi)
#pragma unroll
      for (int ni = 0; ni < 2; ++ni) {
        f32x4 c = acc[mi][ni];
        c = __builtin_amdgcn_mfma_f32_16x16x32_bf16(a[0][mi], b[0][ni], c, 0, 0, 0);
        c = __builtin_amdgcn_mfma_f32_16x16x32_bf16(a[0][mi], b[1][ni], c, 0, 0, 0);
        c = __builtin_amdgcn_mfma_f32_16x16x32_bf16(a[1][mi], b[0][ni], c, 0, 0, 0);
        c = __builtin_amdgcn_mfma_f32_16x16x32_bf16(a[1][mi], b[1][ni], c, 0, 0, 0);
        acc[mi][ni] = c;
      }
    if (hasSk && w == 0) {
      const ushort_t* sb = lds + 24576 + cur * 2048;
      bf16x8 sa0 = *(const bf16x8*)&sb[kg * 128 + lrow * 8];
      bf16x8 sa1 = *(const bf16x8*)&sb[512 + kg * 128 + lrow * 8];
      bf16x8 sb0 = *(const bf16x8*)&sb[1024 + kg * 128 + lrow * 8];
      bf16x8 sb1 = *(const bf16x8*)&sb[1536 + kg * 128 + lrow * 8];
      skacc = __builtin_amdgcn_mfma_f32_16x16x32_bf16(sa0, sb0, skacc, 0, 0, 0);
      skacc = __builtin_amdgcn_mfma_f32_16x16x32_bf16(sa0, sb1, skacc, 0, 0, 0);
      skacc = __builtin_amdgcn_mfma_f32_16x16x32_bf16(sa1, sb0, skacc, 0, 0, 0);
      skacc = __builtin_amdgcn_mfma_f32_16x16x32_bf16(sa1, sb1, skacc, 0, 0, 0);
    }
    if (ks < 31) __builtin_amdgcn_s_barrier();
  }

  // ---- squaring epilogue ----
#pragma unroll
  for (int mi = 0; mi < 2; ++mi)
#pragma unroll
    for (int ni = 0; ni < 2; ++ni) {
      int rowb = m0 + wm + mi * 16 + kg * 4;
      int col = n0 + wn + ni * 16 + lrow;
      float vv[4];
#pragma unroll
      for (int j = 0; j < 4; ++j) vv[j] = acc[mi][ni][j];
      if (flags & FW_TPRE) {
        ushort_t h[4], m[4];
#pragma unroll
        for (int j = 0; j < 4; ++j) split2(vv[j], h[j], m[j]);
        size_t o = (size_t)col * N_DIM + rowb;
        *(ushort4*)&Oset2[2 * NN + o] = make_ushort4(h[0], h[1], h[2], h[3]);
        *(ushort4*)&Oset2[3 * NN + o] = make_ushort4(m[0], m[1], m[2], m[3]);
      }
      if (flags & FW_ADDD) {
#pragma unroll
        for (int j = 0; j < 4; ++j) vv[j] += D[(size_t)(rowb + j) * N_DIM + col];
      }
      if (flags & FW_F32) {
#pragma unroll
        for (int j = 0; j < 4; ++j) Cf[(size_t)(rowb + j) * N_DIM + col] = vv[j];
      }
      if (flags & FW_MKAB) {
#pragma unroll
        for (int j = 0; j < 4; ++j)
          vv[j] = 2.0f * vv[j] + ((rowb + j) == col ? 1.0f : 0.0f);
      }
      if (flags & (FW_SPLIT | FW_TSPLIT)) {
        ushort_t h[4], m[4];
#pragma unroll
        for (int j = 0; j < 4; ++j) split2(vv[j], h[j], m[j]);
        if (flags & FW_SPLIT) {
#pragma unroll
          for (int j = 0; j < 4; ++j) {
            size_t o = (size_t)(rowb + j) * N_DIM + col;
            Oset[o] = h[j]; Oset[NN + o] = m[j];
          }
        }
        if (flags & FW_TSPLIT) {
          size_t o = (size_t)col * N_DIM + rowb;
          *(ushort4*)&Oset[2 * NN + o] = make_ushort4(h[0], h[1], h[2], h[3]);
          *(ushort4*)&Oset[3 * NN + o] = make_ushort4(m[0], m[1], m[2], m[3]);
        }
      }
    }

  // ---- skinny epilogue ----
  if (hasSk && w == 0) {
    int col = c16 * 16 + lrow;
#pragma unroll
    for (int j = 0; j < 4; ++j) {
      int irl = kg * 4 + j;
      if (rt * 16 + irl < cnt) {
        ushort_t h, m; split2(skacc[j], h, m);
        Ka[(size_t)(dstOff + rt * 16 + irl) * N_DIM + col] = h;
        Ka[KR + (size_t)(dstOff + rt * 16 + irl) * N_DIM + col] = m;
      }
    }
  }
}

// ---------------- combine: Kv[q*128+r] = W[q,:] . V[:,r], full-K ----------
__global__ __launch_bounds__(256) void k_combine(
    const ushort_t* __restrict__ Wset, const ushort_t* __restrict__ Vset,
    float* __restrict__ Kv) {
  const size_t KR = (size_t)128 * N_DIM;
  __shared__ __align__(16) ushort_t lds[15360];
  int t = threadIdx.x;
  int rt = blockIdx.x, ct = blockIdx.y;
  const ushort_t* Ah = Wset;
  const ushort_t* Amm = Wset + KR;
  const ushort_t* Bh = Vset;
  const ushort_t* Bm = Vset + KR;
  const int lane = t & 63, w = t >> 6;
  const int lrow = lane & 15, kg = lane >> 4;

  auto stageS = [&](int buf, int k0) {
    ushort_t* base = lds + buf * 5120;
    if (t < 128) {
      int lvl = t >> 6, rem = t & 63, kcc = rem >> 4, i = rem & 15;
      const ushort_t* src =
          (lvl ? Amm : Ah) + (size_t)(rt * 16 + i) * N_DIM + k0 + kcc * 8;
      __builtin_amdgcn_global_load_lds((const AS1 void*)src,
                                       (AS3 void*)(base + t * 8), 16, 0, 0);
    }
#pragma unroll
    for (int it = 0; it < 2; ++it) {
      int t2 = t + it * 256;
      int lvl = t2 >> 8, rem = t2 & 255, kcc = rem >> 6, c = rem & 63;
      const ushort_t* src =
          (lvl ? Bm : Bh) + (size_t)(ct * 64 + c) * N_DIM + k0 + kcc * 8;
      __builtin_amdgcn_global_load_lds(
          (const AS1 void*)src, (AS3 void*)(base + 1024 + t2 * 8), 16, 0, 0);
    }
  };

  f32x4 acc = (f32x4){0.f, 0.f, 0.f, 0.f};
  const int aO = kg * 128 + lrow * 8;
  const int bO = 1024 + kg * 512 + (w * 16 + lrow) * 8;

  stageS(0, 0);
  stageS(1, 32);
  for (int ks = 0; ks < 32; ++ks) {
    int cur = ks % 3;
    if (ks < 30) {
      stageS((ks + 2) % 3, (ks + 2) * 32);
      if (w < 2) asm volatile("s_waitcnt vmcnt(6)" ::: "memory");
      else       asm volatile("s_waitcnt vmcnt(4)" ::: "memory");
    } else if (ks == 30) {
      if (w < 2) asm volatile("s_waitcnt vmcnt(3)" ::: "memory");
      else       asm volatile("s_waitcnt vmcnt(2)" ::: "memory");
    } else {
      asm volatile("s_waitcnt vmcnt(0)" ::: "memory");
    }
    __builtin_amdgcn_s_barrier();
    __builtin_amdgcn_sched_barrier(0);
    const ushort_t* b = lds + cur * 5120;
    bf16x8 a0 = *(const bf16x8*)&b[aO];
    bf16x8 a1 = *(const bf16x8*)&b[aO + 512];
    bf16x8 b0v = *(const bf16x8*)&b[bO];
    bf16x8 b1v = *(const bf16x8*)&b[bO + 2048];
    acc = __builtin_amdgcn_mfma_f32_16x16x32_bf16(a0, b0v, acc, 0, 0, 0);
    acc = __builtin_amdgcn_mfma_f32_16x16x32_bf16(a0, b1v, acc, 0, 0, 0);
    acc = __builtin_amdgcn_mfma_f32_16x16x32_bf16(a1, b0v, acc, 0, 0, 0);
    acc = __builtin_amdgcn_mfma_f32_16x16x32_bf16(a1, b1v, acc, 0, 0, 0);
    if (ks < 31) __builtin_amdgcn_s_barrier();
  }

  int rcol = ct * 64 + w * 16 + lrow;
#pragma unroll
  for (int j = 0; j < 4; ++j) {
    int q = rt * 16 + kg * 4 + j;
    Kv[q * 128 + rcol] = acc[j];
  }
}

// ---------------- causal convolution --------------------------------------
__global__ __launch_bounds__(256) void conv_k(const float* __restrict__ Kv,
    const float* __restrict__ u, float* __restrict__ y) {
  const int CT = 1024, CJ = 256, LCH = 1024;
  int t0 = blockIdx.x * CT;
  int l0 = blockIdx.y * LCH;
  if (l0 > t0 + CT - 1) return;
  __shared__ __align__(16) float Ks[CJ];
  __shared__ __align__(16) float us[CT + CJ + 8];
  int tid = threadIdx.x;
  float acc0 = 0.f, acc1 = 0.f, acc2 = 0.f, acc3 = 0.f;
  int ltEnd = l0 + LCH; if (ltEnd > t0 + CT) ltEnd = t0 + CT;
  for (int lt = l0; lt < ltEnd; lt += CJ) {
    __syncthreads();
    Ks[tid] = Kv[lt + tid];
    int ub = t0 - lt - (CJ - 1);
    for (int s = tid; s < CT + CJ + 4; s += 256) {
      int g = ub + s;
      us[s] = (g >= 0 && g < L_SEQ) ? u[g] : 0.f;
    }
    __syncthreads();
    const float4* u4 = (const float4*)us;
    float4 wa = u4[tid];
#pragma unroll 4
    for (int jb = 0; jb < CJ / 4; ++jb) {
      float4 wb = u4[tid + jb + 1];
      float4 k4 = *(const float4*)&Ks[CJ - 4 - (jb << 2)];
      acc0 += k4.w * wa.x + k4.z * wa.y + k4.y * wa.z + k4.x * wa.w;
      acc1 += k4.w * wa.y + k4.z * wa.z + k4.y * wa.w + k4.x * wb.x;
      acc2 += k4.w * wa.z + k4.z * wa.w + k4.y * wb.x + k4.x * wb.y;
      acc3 += k4.w * wa.w + k4.z * wb.x + k4.y * wb.y + k4.x * wb.z;
      wa = wb;
    }
  }
  int t = t0 + (tid << 2);
  atomicAdd(&y[t + 0], acc0);
  atomicAdd(&y[t + 1], acc1);
  atomicAdd(&y[t + 2], acc2);
  atomicAdd(&y[t + 3], acc3);
}

// ---------------- host ----------------

extern "C" void kernel_launch(void* const* d_in, const int* in_sizes, int n_in,
                              void* d_out, int out_size, void* d_ws, size_t ws_size,
                              hipStream_t stream) {
  const float* u  = (const float*)d_in[0];
  const float* A  = (const float*)d_in[1];
  const float* B  = (const float*)d_in[2];
  const float* Cm = (const float*)d_in[3];
  const float* ls = (const float*)d_in[4];
  float* y  = (float*)d_out;
  float* ws = (float*)d_ws;

  const int N = N_DIM;
  const size_t NN = (size_t)N * N;
  const size_t KR = (size_t)128 * N;
  float* b0 = ws;                     // E -> S
  float* b2 = b0 + NN;                // S1
  float* Kv = b2 + NN;                // L (=128*128)
  ushort_t* setA = (ushort_t*)(Kv + L_SEQ);
  ushort_t* setB = setA + 4 * NN;
  ushort_t* setC = setB + 4 * NN;
  ushort_t* VTset = setC + 4 * NN;    // {H,M} each 128xN
  ushort_t* Wset = VTset + 2 * KR;

  hipMemsetAsync(y, 0, (size_t)L_SEQ * sizeof(float), stream);

  dim3 g16(16, 16);
  dim3 gQ32(16, 8);     // 128 quarter-tiles for 32-row chains

  // E = (step/2)*A ; 4-plane splits -> setA
  k_scalesplit<<<g16, 256, 0, stream>>>(A, ls, b0, setA);
  // E2 = E*E; epilogue: T-splits(E2)->setB, S1=E2+E f32->b2, row-splits(S1)->setC
  gemm4f<<<g16, 256, 0, stream>>>(setA, setA + 2 * NN, b0, b2, setC, setB,
                                  FW_TPRE | FW_ADDD | FW_F32 | FW_SPLIT,
                                  nullptr, nullptr, 0, 0, 0, 0);
  // S = S1*E2 + S1; epilogue: f32 S->b0, Ab=2S+I 4 planes -> setA
  gemm4f<<<g16, 256, 0, stream>>>(setC, setB + 2 * NN, b2, b0, setA, nullptr,
                                  FW_ADDD | FW_F32 | FW_MKAB | FW_SPLIT | FW_TSPLIT,
                                  nullptr, nullptr, 0, 0, 0, 0);
  // VT row0 = split(Bb); W row0 = split(C)
  k_bbinit<<<260, 256, 0, stream>>>(VTset, Wset, b0, B, Cm, ls);

  // 12 fused steps (e=0..11): squaring with INTERLEAVED skinny quarters.
  ushort_t* cur = setA;
  ushort_t* oth = setB;
  for (int e = 0; e < 12; ++e) {
    int right = (e < 7);
    int s = 1 << (right ? e : (e - 7));
    ushort_t* Ka = right ? VTset : Wset;
    const ushort_t* SkB = right ? cur : cur + 2 * NN;
    int fl = (e == 11) ? FW_TSPLIT : (FW_SPLIT | FW_TSPLIT);
    gemm4f<<<g16, 256, 0, stream>>>(cur, cur + 2 * NN, nullptr, nullptr,
                                    oth, nullptr, fl, SkB, Ka, 0, s, s, 1);
    ushort_t* tmp = cur; cur = oth; oth = tmp;
  }
  // cur = Ab^4096. Build W rows [32,128) via 3 chained 32-row quarter passes.
  const ushort_t* Q12T = cur + 2 * NN;
  for (int p = 0; p < 3; ++p)
    gemm4f<<<gQ32, 256, 0, stream>>>(cur, cur, nullptr, nullptr,
                                     nullptr, nullptr, 0, Q12T, Wset,
                                     32 * p, 32 + 32 * p, 32, 2);
  // K = W . V  (full-K, no atomics)
  k_combine<<<dim3(8, 2), 256, 0, stream>>>(Wset, VTset, Kv);
  // y = causal conv(K, u)
  conv_k<<<g16, 256, 0, stream>>>(Kv, u, y);
}